// Round 3
// baseline (620.087 us; speedup 1.0000x reference)
//
#include <hip/hip_runtime.h>
#include <stdint.h>

// Farthest point sampling, NPOINT=2, input [1,B,3,N] fp32 channel-major.
// k1: per-batch partial argmax of y-channel (+ zero the per-batch counters)
// k2: per-block redundant reduce of k1 partials -> f0; distance scan partials;
//     last block per batch (threadfence+atomic counter) reduces -> writes out.
// Output: int32 [B,2] = {f0, f1} per batch.

#define TPB 256  // threads per block (4 waves)
#define BPB 64   // blocks per batch (total grid = B*BPB = 2048 blocks)

typedef unsigned long long u64;

__device__ __forceinline__ u64 umax64(u64 a, u64 b) { return a > b ? a : b; }

// Monotone (order-preserving) mapping f32 -> u32.
__device__ __forceinline__ uint32_t f32_sortable(float f) {
    uint32_t b = __float_as_uint(f);
    return (b & 0x80000000u) ? ~b : (b | 0x80000000u);
}

// Encode (value, index): max-reduce picks max value; ties -> SMALLEST index
// (JAX argmax first-occurrence semantics).
__device__ __forceinline__ u64 enc(float f, uint32_t idx) {
    return ((u64)f32_sortable(f) << 32) | (u64)(0xFFFFFFFFu - idx);
}

__device__ __forceinline__ int dec_idx(u64 e) {
    return (int)(0xFFFFFFFFu - (uint32_t)(e & 0xFFFFFFFFull));
}

// Max of 4 floats with first-index tie-break (strict > keeps earliest), then encode.
__device__ __forceinline__ u64 enc4(float d0, float d1, float d2, float d3, uint32_t i0) {
    float bd = d0; uint32_t bi = i0;
    if (d1 > bd) { bd = d1; bi = i0 + 1; }
    if (d2 > bd) { bd = d2; bi = i0 + 2; }
    if (d3 > bd) { bd = d3; bi = i0 + 3; }
    return enc(bd, bi);
}

// Tree reduce over TPB entries in LDS; result valid in s[0] for ALL threads on return.
__device__ __forceinline__ u64 block_reduce(u64 v, u64* s) {
    s[threadIdx.x] = v;
    __syncthreads();
    for (int off = TPB / 2; off > 0; off >>= 1) {
        if (threadIdx.x < off) s[threadIdx.x] = umax64(s[threadIdx.x], s[threadIdx.x + off]);
        __syncthreads();
    }
    return s[0];
}

// ---- k1: partial argmax over y channel; zero per-batch counters ----
__global__ __launch_bounds__(TPB) void k1_argmax_y(const float* __restrict__ xyz, int N, int B,
                                                   u64* __restrict__ part1,
                                                   uint32_t* __restrict__ cnt) {
    if (blockIdx.x == 0 && threadIdx.x < (uint32_t)B) cnt[threadIdx.x] = 0;

    const int b  = blockIdx.x / BPB;
    const int cb = blockIdx.x % BPB;
    const float4* y4 = (const float4*)(xyz + ((size_t)b * 3 + 1) * (size_t)N);
    const int V = N >> 2;

    u64 best = 0;  // below any real encoded value
    for (int i = cb * TPB + threadIdx.x; i < V; i += BPB * TPB) {
        float4 v = y4[i];
        best = umax64(best, enc4(v.x, v.y, v.z, v.w, (uint32_t)i * 4u));
    }
    __shared__ u64 s[TPB];
    u64 r = block_reduce(best, s);
    if (threadIdx.x == 0) part1[blockIdx.x] = r;
}

// ---- k2: f0 from partials (redundant per block), distance scan, last-block finish ----
__global__ __launch_bounds__(TPB) void k2_dist(const float* __restrict__ xyz, int N,
                                               const u64* __restrict__ part1,
                                               u64* __restrict__ part2,
                                               uint32_t* __restrict__ cnt,
                                               int* __restrict__ out) {
    const int b  = blockIdx.x / BPB;
    const int cb = blockIdx.x % BPB;
    __shared__ u64 s[TPB];
    __shared__ int lastflag;

    // f0: reduce the BPB pass-1 partials of this batch (each block redundantly, ~L2 hits)
    u64 v = (threadIdx.x < BPB) ? part1[b * BPB + threadIdx.x] : 0;
    u64 f0enc = block_reduce(v, s);
    const int c = dec_idx(f0enc);

    const float* xb = xyz + (size_t)b * 3 * (size_t)N;
    const float cx = xb[c];
    const float cy = xb[(size_t)N + c];
    const float cz = xb[2 * (size_t)N + c];

    const float4* x4 = (const float4*)xb;
    const float4* y4 = (const float4*)(xb + N);
    const float4* z4 = (const float4*)(xb + 2 * (size_t)N);
    const int V = N >> 2;

    u64 best = 0;
    for (int i = cb * TPB + threadIdx.x; i < V; i += BPB * TPB) {
        float4 vx = x4[i];
        float4 vy = y4[i];
        float4 vz = z4[i];
        float dx, dy, dz;
        dx = vx.x - cx; dy = vy.x - cy; dz = vz.x - cz;
        const float d0 = dx * dx + dy * dy + dz * dz;
        dx = vx.y - cx; dy = vy.y - cy; dz = vz.y - cz;
        const float d1 = dx * dx + dy * dy + dz * dz;
        dx = vx.z - cx; dy = vy.z - cy; dz = vz.z - cz;
        const float d2 = dx * dx + dy * dy + dz * dz;
        dx = vx.w - cx; dy = vy.w - cy; dz = vz.w - cz;
        const float d3 = dx * dx + dy * dy + dz * dz;
        best = umax64(best, enc4(d0, d1, d2, d3, (uint32_t)i * 4u));
    }
    __syncthreads();  // s[] reuse hazard: everyone past f0 reduce
    u64 r = block_reduce(best, s);

    if (threadIdx.x == 0) {
        part2[blockIdx.x] = r;
        __threadfence();  // make part2 visible device-wide before signaling
        uint32_t old = atomicAdd(&cnt[b], 1u);
        lastflag = (old == BPB - 1) ? 1 : 0;
    }
    __syncthreads();

    if (lastflag) {
        __threadfence();  // acquire side
        volatile const u64* p2 = (volatile const u64*)part2;
        u64 w = (threadIdx.x < BPB) ? p2[b * BPB + threadIdx.x] : 0;
        __syncthreads();  // s[] reuse
        u64 f1enc = block_reduce(w, s);
        if (threadIdx.x == 0) {
            out[b * 2 + 0] = c;
            out[b * 2 + 1] = dec_idx(f1enc);
        }
    }
}

extern "C" void kernel_launch(void* const* d_in, const int* in_sizes, int n_in,
                              void* d_out, int out_size, void* d_ws, size_t ws_size,
                              hipStream_t stream) {
    const float* xyz = (const float*)d_in[0];
    int* out = (int*)d_out;

    const int B = out_size / 2;              // 32
    const int N = in_sizes[0] / (3 * B);     // 1,000,000

    // Workspace (every slot written before read each call; 0xAA poison-safe):
    //   part1: B*BPB u64, part2: B*BPB u64, cnt: B u32 (zeroed by k1)
    u64* part1 = (u64*)d_ws;
    u64* part2 = part1 + (size_t)B * BPB;
    uint32_t* cnt = (uint32_t*)(part2 + (size_t)B * BPB);

    k1_argmax_y<<<B * BPB, TPB, 0, stream>>>(xyz, N, B, part1, cnt);
    k2_dist<<<B * BPB, TPB, 0, stream>>>(xyz, N, part1, part2, cnt, out);
}